// Round 10
// baseline (46.986 us; speedup 1.0000x reference)
//
#include <hip/hip_runtime.h>

#define RADIUS 4
#define KK 81
#define HWP 4096

typedef _Float16 f16x8 __attribute__((ext_vector_type(8)));
typedef float    f32x4 __attribute__((ext_vector_type(4)));

// ws byte-offset layout (f16 channel-last staging)
#define OFF_F1T  0u
#define OFF_L0   4194304u
#define OFF_L1   8388608u
#define OFF_L2   9437184u
#define OFF_L3   9699328u
#define OFF_ZPAD 9764864u        // 512 B of zeros (filled by stage_kernel block 0)
#define OFF_END  9765376u

// ---------- fused staging: all 5 transposes (f32 [B,256,S] -> f16 [B,S,256]) ----------
// R8's scalar variant (measured better than the vectorized R9 version).
__global__ __launch_bounds__(256) void stage_kernel(
    const float* __restrict__ f1, const float* __restrict__ l0,
    const float* __restrict__ l1, const float* __restrict__ l2,
    const float* __restrict__ l3, char* __restrict__ wsB)
{
    __shared__ float tile[32][33];
    const int bx = blockIdx.x;    // 0..297
    const int b  = blockIdx.z;
    const int r0 = blockIdx.y * 32;
    const int tx = threadIdx.x, ty = threadIdx.y;   // 32 x 8
    if (bx == 0 && blockIdx.y == 0 && b == 0) {
        const int tt = ty * 32 + tx;
        if (tt < 128) ((float*)(wsB + OFF_ZPAD))[tt] = 0.0f;   // zero pad record
    }
    const float* src; _Float16* dst; int S, s0i;
    if (bx < 128)      { src = f1; dst = (_Float16*)(wsB + OFF_F1T); S = 4096; s0i = bx; }
    else if (bx < 256) { src = l0; dst = (_Float16*)(wsB + OFF_L0);  S = 4096; s0i = bx - 128; }
    else if (bx < 288) { src = l1; dst = (_Float16*)(wsB + OFF_L1);  S = 1024; s0i = bx - 256; }
    else if (bx < 296) { src = l2; dst = (_Float16*)(wsB + OFF_L2);  S = 256;  s0i = bx - 288; }
    else               { src = l3; dst = (_Float16*)(wsB + OFF_L3);  S = 64;   s0i = bx - 296; }
    const int s0 = s0i * 32;
    src += (size_t)b * 256 * S;
    dst += (size_t)b * S * 256;
    #pragma unroll
    for (int i = 0; i < 32; i += 8)
        tile[ty + i][tx] = src[(size_t)(r0 + ty + i) * S + s0 + tx];
    __syncthreads();
    #pragma unroll
    for (int i = 0; i < 32; i += 8)
        dst[(size_t)(s0 + ty + i) * 256 + r0 + tx] = (_Float16)tile[tx][ty + i];
}

// ---------- main: 8x8-px tiles (64 px), single-unit phases, R8 machinery ----------
// R10: ONE change vs R8 (best, 43.96us) -- tile 8x4 -> 8x8 px. Each staged 8-KB
// unit is consumed by ALL 4 waves (each owns one 16-px A-set -> 32 MFMA/unit
// instead of 16), so the gathered window amortizes over 2x pixels: requested
// gather bytes ~200 -> ~105 MB. Everything else identical: granule LDS layout,
// scatter, sD stride 106, setprio, 3 blocks/CU (LDS ~45KB).
__global__ __launch_bounds__(256, 3) void corr_mfma_kernel(
    const char* __restrict__ wsB,
    const float* __restrict__ coords,
    float* __restrict__ out)           // [B,324,4096]
{
    __shared__ f32x4 sB[2][512];       // 2 x 8KB double-buffered unit
    __shared__ float sD[64][106];      // per-px 10x10 window dots (padded stride)
    __shared__ int   sIx[64], sIy[64];
    __shared__ float sW[64][4];
    __shared__ int   sBox[5];          // rlo, cfi, ntw, ntot, inv

    char* sBb = (char*)sB;

    const int bx   = blockIdx.x;                  // 0..127
    const int lvl  = blockIdx.y;                  // 0..3
    const int tile = ((bx & 7) << 4) | (bx >> 3); // XCD swizzle (bijective on 128)
    const int b    = tile >> 6;
    const int t6   = tile & 63;                   // 8x8 grid of 8x8-px tiles
    const int tr8  = (t6 >> 3) << 3;              // tile pixel-row base (8 tall)
    const int tc8  = (t6 & 7) << 3;               // tile pixel-col base (8 wide)
    const int t    = threadIdx.x;                 // 0..255
    const int l    = t & 63;
    const int wid  = t >> 6;                      // wave 0..3 = A-set id

    const int sh = 6 - lvl;
    const int W2 = 1 << sh;

    for (int i = t; i < 64 * 106; i += 256)
        ((float*)sD)[i] = 0.0f;

    if (t < 64) {
        const int hwc = ((tr8 + (t >> 3)) << 6) + tc8 + (t & 7);
        const float sc = 1.0f / (float)(1 << lvl);
        const float xs = coords[((size_t)b * 2 + 0) * HWP + hwc] * sc;
        const float ys = coords[((size_t)b * 2 + 1) * HWP + hwc] * sc;
        const float x0f = floorf(xs), y0f = floorf(ys);
        sIx[t] = (int)x0f; sIy[t] = (int)y0f;
        const float fx = xs - x0f, fy = ys - y0f;
        sW[t][0] = (1.f - fx) * (1.f - fy);
        sW[t][1] = fx * (1.f - fy);
        sW[t][2] = (1.f - fx) * fy;
        sW[t][3] = fx * fy;
    }
    __syncthreads();
    if (t == 0) {
        int rlo = 1 << 20, rhi = -(1 << 20), clo = 1 << 20, chi = -(1 << 20);
        for (int px = 0; px < 64; ++px) {
            rlo = min(rlo, sIy[px]); rhi = max(rhi, sIy[px]);
            clo = min(clo, sIx[px]); chi = max(chi, sIx[px]);
        }
        const int rl = max(rlo - RADIUS, 0);
        const int rh = min(rhi + RADIUS + 1, W2 - 1);
        const int cf = max(clo - RADIUS, 0);
        const int ce = min(chi + RADIUS + 1, W2 - 1);
        const int nr = rh - rl + 1;
        const int nt = (ce >= cf) ? ((ce - cf + 16) >> 4) : 0;
        sBox[0] = rl;
        sBox[1] = cf;
        sBox[2] = nt;
        sBox[3] = (nr > 0) ? nr * nt : 0;
        sBox[4] = 65535 / max(nt, 1) + 1;     // exact u/nt = (u*inv)>>16 for u<512,nt<=8
    }

    // A fragments (verified mapping): wave wid owns px wid*16+(l&15); k-chunk (l>>4)
    const int pxl = (wid << 4) + (l & 15);
    const int hwA = ((tr8 + (pxl >> 3)) << 6) + tc8 + (pxl & 7);
    const char* ap = wsB + OFF_F1T + ((size_t)(b * HWP + hwA)) * 512 + ((l >> 4) << 4);
    const f16x8 a0 = __builtin_bit_cast(f16x8, *(const f32x4*)(ap));
    const f16x8 a1 = __builtin_bit_cast(f16x8, *(const f32x4*)(ap + 64));
    const f16x8 a2 = __builtin_bit_cast(f16x8, *(const f32x4*)(ap + 128));
    const f16x8 a3 = __builtin_bit_cast(f16x8, *(const f32x4*)(ap + 192));
    const f16x8 a4 = __builtin_bit_cast(f16x8, *(const f32x4*)(ap + 256));
    const f16x8 a5 = __builtin_bit_cast(f16x8, *(const f32x4*)(ap + 320));
    const f16x8 a6 = __builtin_bit_cast(f16x8, *(const f32x4*)(ap + 384));
    const f16x8 a7 = __builtin_bit_cast(f16x8, *(const f32x4*)(ap + 448));
    __syncthreads();                      // publish sBox

    const int rlo = sBox[0], cfi = sBox[1], ntw = sBox[2];
    const int ntot = sBox[3], inv = sBox[4];
    const unsigned lvbase = ((lvl == 0) ? OFF_L0 : (lvl == 1) ? OFF_L1
                           : (lvl == 2) ? OFF_L2 : OFF_L3)
                          + (((unsigned)b << (2 * sh)) << 9);
    const int coff = l & 15;

    const int pxg  = (wid << 4) + ((l >> 4) << 2);   // this lane's 4 scatter pixels
    const int iy0r = sIy[pxg + 0], ix0r = sIx[pxg + 0];
    const int iy1r = sIy[pxg + 1], ix1r = sIx[pxg + 1];
    const int iy2r = sIy[pxg + 2], ix2r = sIx[pxg + 2];
    const int iy3r = sIy[pxg + 3], ix3r = sIx[pxg + 3];

// stage loads for phase P (ONE 8-KB unit): thread t -> px (t&15), granule pair 2*(t>>4)
#define LOADP(P_, R0_, R1_) { \
        const int u_ = (P_); \
        const unsigned q_ = ((unsigned)(u_ * inv)) >> 16; \
        const int j_ = u_ - (int)q_ * ntw; \
        const int col_ = cfi + (j_ << 4) + (t & 15); \
        const bool ok_ = (u_ < ntot) && ((unsigned)col_ < (unsigned)W2); \
        const int row_ = rlo + (int)q_; \
        const char* gp_ = wsB + (ok_ ? (lvbase + ((unsigned)((row_ << sh) + col_) << 9)) \
                                     : OFF_ZPAD) + ((unsigned)(t >> 4) << 5); \
        R0_ = *(const f32x4*)(gp_); \
        R1_ = *(const f32x4*)(gp_ + 16); \
        __builtin_amdgcn_sched_barrier(0); }

// LDS layout: byte = g*256 + px*16 (granule g = 16B of channels) -- R8-identical map
#define WRITEP(BUF_, R0_, R1_) { \
        char* wp_ = sBb + ((BUF_) << 13) + ((t >> 4) << 9) + ((t & 15) << 4); \
        *(f32x4*)(wp_)       = R0_; \
        *(f32x4*)(wp_ + 256) = R1_; }

// consume phase P's unit with this wave's A-set: 8 ds_read_b128 + 8 MFMA + scatter
#define CONSUMEP(BUF_, P_) { \
        const int u_ = (P_); \
        if (u_ < ntot) { \
            const unsigned q_ = ((unsigned)(u_ * inv)) >> 16; \
            const int j_ = u_ - (int)q_ * ntw; \
            const int row_ = rlo + (int)q_; \
            const char* lb_ = sBb + ((BUF_) << 13) + ((l >> 4) << 8) + ((l & 15) << 4); \
            const f16x8 b0_ = __builtin_bit_cast(f16x8, *(const f32x4*)(lb_)); \
            const f16x8 b1_ = __builtin_bit_cast(f16x8, *(const f32x4*)(lb_ + 1024)); \
            const f16x8 b2_ = __builtin_bit_cast(f16x8, *(const f32x4*)(lb_ + 2048)); \
            const f16x8 b3_ = __builtin_bit_cast(f16x8, *(const f32x4*)(lb_ + 3072)); \
            const f16x8 b4_ = __builtin_bit_cast(f16x8, *(const f32x4*)(lb_ + 4096)); \
            const f16x8 b5_ = __builtin_bit_cast(f16x8, *(const f32x4*)(lb_ + 5120)); \
            const f16x8 b6_ = __builtin_bit_cast(f16x8, *(const f32x4*)(lb_ + 6144)); \
            const f16x8 b7_ = __builtin_bit_cast(f16x8, *(const f32x4*)(lb_ + 7168)); \
            f32x4 ac0 = {0.f, 0.f, 0.f, 0.f}; \
            f32x4 ac1 = {0.f, 0.f, 0.f, 0.f}; \
            __builtin_amdgcn_s_setprio(1); \
            ac0 = __builtin_amdgcn_mfma_f32_16x16x32_f16(a0, b0_, ac0, 0, 0, 0); \
            ac1 = __builtin_amdgcn_mfma_f32_16x16x32_f16(a1, b1_, ac1, 0, 0, 0); \
            ac0 = __builtin_amdgcn_mfma_f32_16x16x32_f16(a2, b2_, ac0, 0, 0, 0); \
            ac1 = __builtin_amdgcn_mfma_f32_16x16x32_f16(a3, b3_, ac1, 0, 0, 0); \
            ac0 = __builtin_amdgcn_mfma_f32_16x16x32_f16(a4, b4_, ac0, 0, 0, 0); \
            ac1 = __builtin_amdgcn_mfma_f32_16x16x32_f16(a5, b5_, ac1, 0, 0, 0); \
            ac0 = __builtin_amdgcn_mfma_f32_16x16x32_f16(a6, b6_, ac0, 0, 0, 0); \
            ac1 = __builtin_amdgcn_mfma_f32_16x16x32_f16(a7, b7_, ac1, 0, 0, 0); \
            __builtin_amdgcn_s_setprio(0); \
            const f32x4 accs = ac0 + ac1; \
            const int col_ = cfi + (j_ << 4) + coff; \
            const int p0 = row_ - iy0r + RADIUS, q0 = col_ - ix0r + RADIUS; \
            if ((unsigned)p0 < 10u && (unsigned)q0 < 10u) sD[pxg + 0][p0 * 10 + q0] = accs[0]; \
            const int p1 = row_ - iy1r + RADIUS, q1 = col_ - ix1r + RADIUS; \
            if ((unsigned)p1 < 10u && (unsigned)q1 < 10u) sD[pxg + 1][p1 * 10 + q1] = accs[1]; \
            const int p2 = row_ - iy2r + RADIUS, q2 = col_ - ix2r + RADIUS; \
            if ((unsigned)p2 < 10u && (unsigned)q2 < 10u) sD[pxg + 2][p2 * 10 + q2] = accs[2]; \
            const int p3 = row_ - iy3r + RADIUS, q3 = col_ - ix3r + RADIUS; \
            if ((unsigned)p3 < 10u && (unsigned)q3 < 10u) sD[pxg + 3][p3 * 10 + q3] = accs[3]; \
        } }

    {
        f32x4 XA, XB, YA, YB;
        const int NP = ntot;
        if (NP > 0) {
            LOADP(0, XA, XB);
            if (NP > 1) LOADP(1, YA, YB);
            WRITEP(0, XA, XB);
        }
        __syncthreads();                         // buf0 ready
        if (NP > 0) {
            int p = 0;
            for (;;) {
                // body A: X free -> prefetch p+2; consume p; publish p+1 (Y)
                if (p + 2 < NP) LOADP(p + 2, XA, XB);
                CONSUMEP(p & 1, p);
                if (p + 1 < NP) WRITEP((p + 1) & 1, YA, YB);
                __syncthreads();
                if (++p >= NP) break;
                // body B: roles swapped (static reg names, rule #20)
                if (p + 2 < NP) LOADP(p + 2, YA, YB);
                CONSUMEP(p & 1, p);
                if (p + 1 < NP) WRITEP((p + 1) & 1, XA, XB);
                __syncthreads();
                if (++p >= NP) break;
            }
        }
    }
#undef LOADP
#undef WRITEP
#undef CONSUMEP
    __syncthreads();

    // bilinear combine + store (this level's 81 channels, 64 pixels)
    for (int j = t; j < 64 * KK; j += 256) {
        const int px = j & 63;
        const int k  = j >> 6;           // 0..80
        const int p  = (k * 57) >> 9;    // k/9
        const int q  = k - p * 9;
        const int bi = p * 10 + q;
        const float* dd = sD[px];
        const float v = (sW[px][0] * dd[bi]      + sW[px][1] * dd[bi + 1] +
                         sW[px][2] * dd[bi + 10] + sW[px][3] * dd[bi + 11]) * 0.0625f;
        const int hwp = ((tr8 + (px >> 3)) << 6) + tc8 + (px & 7);
        out[((size_t)b * 324 + lvl * KK + k) * HWP + hwp] = v;
    }
}

// ---------- fallback (Round-2 verified, original layouts) ----------
__global__ __launch_bounds__(128) void corr_level_kernel(
    const float* __restrict__ f1, const float* __restrict__ f2,
    const float* __restrict__ coords, float* __restrict__ out,
    int H2, int W2, float scale, int lvl)
{
    __shared__ float sf1[256];
    __shared__ float sDl[100];
    const int pix = blockIdx.x;
    const int b   = pix >> 12;
    const int hw  = pix & 4095;
    const int t   = threadIdx.x;
    for (int c = t; c < 256; c += 128)
        sf1[c] = f1[((size_t)b * 256 + c) * 4096 + hw];
    __syncthreads();
    const float xs = coords[((size_t)b * 2 + 0) * 4096 + hw] * scale;
    const float ys = coords[((size_t)b * 2 + 1) * 4096 + hw] * scale;
    const float x0f = floorf(xs), y0f = floorf(ys);
    const float fx = xs - x0f, fy = ys - y0f;
    const int ix0 = (int)x0f, iy0 = (int)y0f;
    if (t < 100) {
        const int p = t / 10, q = t - p * 10;
        const int row = iy0 - 4 + p, col = ix0 - 4 + q;
        float acc = 0.0f;
        if (row >= 0 && row < H2 && col >= 0 && col < W2) {
            const size_t step = (size_t)H2 * W2;
            const size_t base = (size_t)b * 256 * step + (size_t)row * W2 + col;
            #pragma unroll 4
            for (int c = 0; c < 256; ++c)
                acc += f2[base + (size_t)c * step] * sf1[c];
        }
        sDl[t] = acc;
    }
    __syncthreads();
    if (t < 81) {
        const int p = t / 9, q = t - p * 9;
        const float d00 = sDl[p * 10 + q];
        const float d01 = sDl[p * 10 + q + 1];
        const float d10 = sDl[p * 10 + q + 10];
        const float d11 = sDl[p * 10 + q + 11];
        const float v = (1.0f - fy) * ((1.0f - fx) * d00 + fx * d01)
                      + fy * ((1.0f - fx) * d10 + fx * d11);
        out[((size_t)b * 324 + (size_t)lvl * 81 + t) * 4096 + hw] = v * 0.0625f;
    }
}

extern "C" void kernel_launch(void* const* d_in, const int* in_sizes, int n_in,
                              void* d_out, int out_size, void* d_ws, size_t ws_size,
                              hipStream_t stream) {
    (void)out_size;
    const float* f1     = (const float*)d_in[0];
    const float* f2l[4] = {(const float*)d_in[1], (const float*)d_in[2],
                           (const float*)d_in[3], (const float*)d_in[4]};
    const float* coords = (const float*)d_in[5];

    // Size-based identification (input order proved unreliable in R1).
    {
        int nbig = 0;
        for (int i = 0; i < n_in; ++i) {
            const int sz = in_sizes[i];
            if (sz == 2097152) {
                if (nbig == 0) f1 = (const float*)d_in[i];
                else           f2l[0] = (const float*)d_in[i];
                ++nbig;
            }
            else if (sz == 524288) f2l[1] = (const float*)d_in[i];
            else if (sz == 131072) f2l[2] = (const float*)d_in[i];
            else if (sz ==  32768) f2l[3] = (const float*)d_in[i];
            else if (sz ==  16384) coords = (const float*)d_in[i];
        }
    }
    float* out = (float*)d_out;
    char*  wsB = (char*)d_ws;

    if (ws_size >= (size_t)OFF_END) {
        stage_kernel<<<dim3(298, 8, 2), dim3(32, 8, 1), 0, stream>>>(
            f1, f2l[0], f2l[1], f2l[2], f2l[3], wsB);
        corr_mfma_kernel<<<dim3(128, 4, 1), 256, 0, stream>>>(wsB, coords, out);
    } else {
        for (int lvl = 0; lvl < 4; ++lvl) {
            const int W2 = 64 >> lvl;
            const float scale = 1.0f / (float)(1 << lvl);
            corr_level_kernel<<<8192, 128, 0, stream>>>(
                f1, f2l[lvl], coords, out, W2, W2, scale, lvl);
        }
    }
}

// Round 11
// 45.612 us; speedup vs baseline: 1.0301x; 1.0301x over previous
//
#include <hip/hip_runtime.h>

#define RADIUS 4
#define KK 81
#define HWP 4096

typedef _Float16 f16x8 __attribute__((ext_vector_type(8)));
typedef float    f32x4 __attribute__((ext_vector_type(4)));

// ws byte-offset layout (f16 channel-last staging)
#define OFF_F1T  0u
#define OFF_L0   4194304u
#define OFF_L1   8388608u
#define OFF_L2   9437184u
#define OFF_L3   9699328u
#define OFF_ZPAD 9764864u        // 512 B of zeros (filled by stage_kernel block 0)
#define OFF_END  9765376u

// ---------- fused staging: all 5 transposes (f32 [B,256,S] -> f16 [B,S,256]) ----------
// R8's scalar variant (measured better than the vectorized R9 version).
__global__ __launch_bounds__(256) void stage_kernel(
    const float* __restrict__ f1, const float* __restrict__ l0,
    const float* __restrict__ l1, const float* __restrict__ l2,
    const float* __restrict__ l3, char* __restrict__ wsB)
{
    __shared__ float tile[32][33];
    const int bx = blockIdx.x;    // 0..297
    const int b  = blockIdx.z;
    const int r0 = blockIdx.y * 32;
    const int tx = threadIdx.x, ty = threadIdx.y;   // 32 x 8
    if (bx == 0 && blockIdx.y == 0 && b == 0) {
        const int tt = ty * 32 + tx;
        if (tt < 128) ((float*)(wsB + OFF_ZPAD))[tt] = 0.0f;   // zero pad record
    }
    const float* src; _Float16* dst; int S, s0i;
    if (bx < 128)      { src = f1; dst = (_Float16*)(wsB + OFF_F1T); S = 4096; s0i = bx; }
    else if (bx < 256) { src = l0; dst = (_Float16*)(wsB + OFF_L0);  S = 4096; s0i = bx - 128; }
    else if (bx < 288) { src = l1; dst = (_Float16*)(wsB + OFF_L1);  S = 1024; s0i = bx - 256; }
    else if (bx < 296) { src = l2; dst = (_Float16*)(wsB + OFF_L2);  S = 256;  s0i = bx - 288; }
    else               { src = l3; dst = (_Float16*)(wsB + OFF_L3);  S = 64;   s0i = bx - 296; }
    const int s0 = s0i * 32;
    src += (size_t)b * 256 * S;
    dst += (size_t)b * S * 256;
    #pragma unroll
    for (int i = 0; i < 32; i += 8)
        tile[ty + i][tx] = src[(size_t)(r0 + ty + i) * S + s0 + tx];
    __syncthreads();
    #pragma unroll
    for (int i = 0; i < 32; i += 8)
        dst[(size_t)(s0 + ty + i) * 256 + r0 + tx] = (_Float16)tile[tx][ty + i];
}

// in-loop barrier: wait LDS ops only; prefetch global loads stay in flight across it
// (__syncthreads would drain vmcnt(0) every phase -- the m97 barrier-drain stall)
#define BARRIER_LW { asm volatile("s_waitcnt lgkmcnt(0)" ::: "memory"); \
                     __builtin_amdgcn_s_barrier(); \
                     __builtin_amdgcn_sched_barrier(0); }

// ---------- main: 8x4-pixel tiles (32 px), paired-unit LDS pipeline ----------
// R11 = EXACT R8 machinery (best, 43.96us: sD stride 106 + setprio + scalar stage)
// with the loop upgraded to LW barriers + DEPTH-3 X/Y/Z register rotation:
// each unit-pair's global loads are issued ~2.5 phases before their ds_write,
// giving ~700-900 cyc of latency cover instead of a synchronous per-phase drain.
__global__ __launch_bounds__(256, 3) void corr_mfma_kernel(
    const char* __restrict__ wsB,
    const float* __restrict__ coords,
    float* __restrict__ out)           // [B,324,4096]
{
    __shared__ f32x4 sB[2][1024];      // 2 x 16KB (two 8-KB unit-halves each)
    __shared__ float sD[32][106];      // per-px 10x10 window dots (padded stride)
    __shared__ int   sIx[32], sIy[32];
    __shared__ float sW[32][4];
    __shared__ int   sBox[5];          // rlo, cfi, ntw, ntot, inv

    char* sBb = (char*)sB;

    const int bx   = blockIdx.x;                  // 0..255
    const int lvl  = blockIdx.y;                  // 0..3
    const int tile = ((bx & 7) << 5) | (bx >> 3); // XCD swizzle (bijective on 256)
    const int b    = tile >> 7;
    const int t7   = tile & 127;                  // 128 tiles per batch: 16 rows x 8 cols
    const int tr4  = (t7 >> 3) << 2;              // tile pixel-row base (4 tall)
    const int tc8  = (t7 & 7) << 3;               // tile pixel-col base (8 wide)
    const int t    = threadIdx.x;                 // 0..255
    const int l    = t & 63;
    const int wid  = t >> 6;                      // wave 0..3
    const int aset = wid & 1;                     // which 16-px A tile
    const int half = wid >> 1;                    // which unit of the pair

    const int sh = 6 - lvl;
    const int W2 = 1 << sh;

    for (int i = t; i < 32 * 106; i += 256)
        ((float*)sD)[i] = 0.0f;

    if (t < 32) {
        const int hwc = ((tr4 + (t >> 3)) << 6) + tc8 + (t & 7);
        const float sc = 1.0f / (float)(1 << lvl);
        const float xs = coords[((size_t)b * 2 + 0) * HWP + hwc] * sc;
        const float ys = coords[((size_t)b * 2 + 1) * HWP + hwc] * sc;
        const float x0f = floorf(xs), y0f = floorf(ys);
        sIx[t] = (int)x0f; sIy[t] = (int)y0f;
        const float fx = xs - x0f, fy = ys - y0f;
        sW[t][0] = (1.f - fx) * (1.f - fy);
        sW[t][1] = fx * (1.f - fy);
        sW[t][2] = (1.f - fx) * fy;
        sW[t][3] = fx * fy;
    }
    __syncthreads();
    if (t == 0) {
        int rlo = 1 << 20, rhi = -(1 << 20), clo = 1 << 20, chi = -(1 << 20);
        for (int px = 0; px < 32; ++px) {
            rlo = min(rlo, sIy[px]); rhi = max(rhi, sIy[px]);
            clo = min(clo, sIx[px]); chi = max(chi, sIx[px]);
        }
        const int rl = max(rlo - RADIUS, 0);
        const int rh = min(rhi + RADIUS + 1, W2 - 1);
        const int cf = max(clo - RADIUS, 0);
        const int ce = min(chi + RADIUS + 1, W2 - 1);
        const int nr = rh - rl + 1;
        const int nt = (ce >= cf) ? ((ce - cf + 16) >> 4) : 0;
        sBox[0] = rl;
        sBox[1] = cf;
        sBox[2] = nt;
        sBox[3] = (nr > 0) ? nr * nt : 0;
        sBox[4] = 65535 / max(nt, 1) + 1;     // exact u/nt = (u*inv)>>16 for u<512,nt<=8
    }

    // A fragments (verified R9 mapping): lane l = local px (l&15) in A-set, k-chunk (l>>4)
    const int pxl = (aset << 4) + (l & 15);
    const int hwA = ((tr4 + (pxl >> 3)) << 6) + tc8 + (pxl & 7);
    const char* ap = wsB + OFF_F1T + ((size_t)(b * HWP + hwA)) * 512 + ((l >> 4) << 4);
    const f16x8 a0 = __builtin_bit_cast(f16x8, *(const f32x4*)(ap));
    const f16x8 a1 = __builtin_bit_cast(f16x8, *(const f32x4*)(ap + 64));
    const f16x8 a2 = __builtin_bit_cast(f16x8, *(const f32x4*)(ap + 128));
    const f16x8 a3 = __builtin_bit_cast(f16x8, *(const f32x4*)(ap + 192));
    const f16x8 a4 = __builtin_bit_cast(f16x8, *(const f32x4*)(ap + 256));
    const f16x8 a5 = __builtin_bit_cast(f16x8, *(const f32x4*)(ap + 320));
    const f16x8 a6 = __builtin_bit_cast(f16x8, *(const f32x4*)(ap + 384));
    const f16x8 a7 = __builtin_bit_cast(f16x8, *(const f32x4*)(ap + 448));
    __syncthreads();                      // publish sBox (prologue; full drain OK here)

    const int rlo = sBox[0], cfi = sBox[1], ntw = sBox[2];
    const int ntot = sBox[3], inv = sBox[4];
    const int NP = (ntot + 1) >> 1;       // phases (2 units each)
    const unsigned lvbase = ((lvl == 0) ? OFF_L0 : (lvl == 1) ? OFF_L1
                           : (lvl == 2) ? OFF_L2 : OFF_L3)
                          + (((unsigned)b << (2 * sh)) << 9);
    const int coff = l & 15;

    const int pxg  = (aset << 4) + ((l >> 4) << 2);  // this lane's 4 scatter pixels
    const int iy0r = sIy[pxg + 0], ix0r = sIx[pxg + 0];
    const int iy1r = sIy[pxg + 1], ix1r = sIx[pxg + 1];
    const int iy2r = sIy[pxg + 2], ix2r = sIx[pxg + 2];
    const int iy3r = sIy[pxg + 3], ix3r = sIx[pxg + 3];

// stage loads for phase P: thread t serves unit u=2P+(t>>7), px (t&15), 64B at chunk-group (t>>4)&7
#define LOADP(P_, R0_, R1_, R2_, R3_) { \
        const int u_ = ((P_) << 1) + (t >> 7); \
        const unsigned q_ = ((unsigned)(u_ * inv)) >> 16; \
        const int j_ = u_ - (int)q_ * ntw; \
        const int col_ = cfi + (j_ << 4) + (t & 15); \
        const bool ok_ = (u_ < ntot) && ((unsigned)col_ < (unsigned)W2); \
        const int row_ = rlo + (int)q_; \
        const char* gp_ = wsB + (ok_ ? (lvbase + ((unsigned)((row_ << sh) + col_) << 9)) \
                                     : OFF_ZPAD) + ((unsigned)((t >> 4) & 7) << 6); \
        R0_ = *(const f32x4*)(gp_); \
        R1_ = *(const f32x4*)(gp_ + 16); \
        R2_ = *(const f32x4*)(gp_ + 32); \
        R3_ = *(const f32x4*)(gp_ + 48); \
        __builtin_amdgcn_sched_barrier(0); }

// LDS layout per 8-KB half: byte = g*256 + px*16 (granule g = 16B of channels), proven R1 map
// (compiler inserts a COUNTED vmcnt before these ds_writes -- only this phase's loads)
#define WRITEP(BUF_, R0_, R1_, R2_, R3_) { \
        char* wp_ = sBb + ((BUF_) << 14) + ((t >> 7) << 13) + (((t >> 4) & 7) << 10) \
                  + ((t & 15) << 4); \
        *(f32x4*)(wp_)       = R0_; \
        *(f32x4*)(wp_ + 256) = R1_; \
        *(f32x4*)(wp_ + 512) = R2_; \
        *(f32x4*)(wp_ + 768) = R3_; }

// consume this wave's unit of phase P: 8 ds_read_b128 + 8 MFMA (setprio-wrapped) + scatter
#define CONSUMEP(BUF_, P_) { \
        const int u_ = ((P_) << 1) + half; \
        if (u_ < ntot) { \
            const unsigned q_ = ((unsigned)(u_ * inv)) >> 16; \
            const int j_ = u_ - (int)q_ * ntw; \
            const int row_ = rlo + (int)q_; \
            const char* lb_ = sBb + ((BUF_) << 14) + (half << 13) + ((l >> 4) << 8) \
                            + ((l & 15) << 4); \
            const f16x8 b0_ = __builtin_bit_cast(f16x8, *(const f32x4*)(lb_)); \
            const f16x8 b1_ = __builtin_bit_cast(f16x8, *(const f32x4*)(lb_ + 1024)); \
            const f16x8 b2_ = __builtin_bit_cast(f16x8, *(const f32x4*)(lb_ + 2048)); \
            const f16x8 b3_ = __builtin_bit_cast(f16x8, *(const f32x4*)(lb_ + 3072)); \
            const f16x8 b4_ = __builtin_bit_cast(f16x8, *(const f32x4*)(lb_ + 4096)); \
            const f16x8 b5_ = __builtin_bit_cast(f16x8, *(const f32x4*)(lb_ + 5120)); \
            const f16x8 b6_ = __builtin_bit_cast(f16x8, *(const f32x4*)(lb_ + 6144)); \
            const f16x8 b7_ = __builtin_bit_cast(f16x8, *(const f32x4*)(lb_ + 7168)); \
            f32x4 ac0 = {0.f, 0.f, 0.f, 0.f}; \
            f32x4 ac1 = {0.f, 0.f, 0.f, 0.f}; \
            __builtin_amdgcn_s_setprio(1); \
            ac0 = __builtin_amdgcn_mfma_f32_16x16x32_f16(a0, b0_, ac0, 0, 0, 0); \
            ac1 = __builtin_amdgcn_mfma_f32_16x16x32_f16(a1, b1_, ac1, 0, 0, 0); \
            ac0 = __builtin_amdgcn_mfma_f32_16x16x32_f16(a2, b2_, ac0, 0, 0, 0); \
            ac1 = __builtin_amdgcn_mfma_f32_16x16x32_f16(a3, b3_, ac1, 0, 0, 0); \
            ac0 = __builtin_amdgcn_mfma_f32_16x16x32_f16(a4, b4_, ac0, 0, 0, 0); \
            ac1 = __builtin_amdgcn_mfma_f32_16x16x32_f16(a5, b5_, ac1, 0, 0, 0); \
            ac0 = __builtin_amdgcn_mfma_f32_16x16x32_f16(a6, b6_, ac0, 0, 0, 0); \
            ac1 = __builtin_amdgcn_mfma_f32_16x16x32_f16(a7, b7_, ac1, 0, 0, 0); \
            __builtin_amdgcn_s_setprio(0); \
            const f32x4 accs = ac0 + ac1; \
            const int col_ = cfi + (j_ << 4) + coff; \
            const int p0 = row_ - iy0r + RADIUS, q0 = col_ - ix0r + RADIUS; \
            if ((unsigned)p0 < 10u && (unsigned)q0 < 10u) sD[pxg + 0][p0 * 10 + q0] = accs[0]; \
            const int p1 = row_ - iy1r + RADIUS, q1 = col_ - ix1r + RADIUS; \
            if ((unsigned)p1 < 10u && (unsigned)q1 < 10u) sD[pxg + 1][p1 * 10 + q1] = accs[1]; \
            const int p2 = row_ - iy2r + RADIUS, q2 = col_ - ix2r + RADIUS; \
            if ((unsigned)p2 < 10u && (unsigned)q2 < 10u) sD[pxg + 2][p2 * 10 + q2] = accs[2]; \
            const int p3 = row_ - iy3r + RADIUS, q3 = col_ - ix3r + RADIUS; \
            if ((unsigned)p3 < 10u && (unsigned)q3 < 10u) sD[pxg + 3][p3 * 10 + q3] = accs[3]; \
        } }

    {
        f32x4 XA, XB, XC, XD, YA, YB, YC, YD, ZA, ZB, ZC, ZD;
        if (ntot > 0) {
            LOADP(0, XA, XB, XC, XD);
            if (NP > 1) LOADP(1, YA, YB, YC, YD);
            if (NP > 2) LOADP(2, ZA, ZB, ZC, ZD);
            WRITEP(0, XA, XB, XC, XD);
        }
        BARRIER_LW;                          // buf0 ready; phase 1,2 loads in flight
        if (ntot > 0) {
            int p = 0;
            for (;;) {
                // body A: X free -> prefetch p+3; consume p; publish p+1 (Y)
                if (p + 3 < NP) LOADP(p + 3, XA, XB, XC, XD);
                CONSUMEP(p & 1, p);
                if (p + 1 < NP) WRITEP((p + 1) & 1, YA, YB, YC, YD);
                BARRIER_LW;
                if (++p >= NP) break;
                // body B: Y free -> prefetch p+3; consume p; publish p+1 (Z)
                if (p + 3 < NP) LOADP(p + 3, YA, YB, YC, YD);
                CONSUMEP(p & 1, p);
                if (p + 1 < NP) WRITEP((p + 1) & 1, ZA, ZB, ZC, ZD);
                BARRIER_LW;
                if (++p >= NP) break;
                // body C: Z free -> prefetch p+3; consume p; publish p+1 (X)
                if (p + 3 < NP) LOADP(p + 3, ZA, ZB, ZC, ZD);
                CONSUMEP(p & 1, p);
                if (p + 1 < NP) WRITEP((p + 1) & 1, XA, XB, XC, XD);
                BARRIER_LW;
                if (++p >= NP) break;
            }
        }
    }
#undef LOADP
#undef WRITEP
#undef CONSUMEP
    __syncthreads();                         // full drain before combine

    // bilinear combine + store (this level's 81 channels, 32 pixels)
    for (int j = t; j < 32 * KK; j += 256) {
        const int px = j & 31;
        const int k  = j >> 5;           // 0..80
        const int p  = (k * 57) >> 9;    // k/9
        const int q  = k - p * 9;
        const int bi = p * 10 + q;
        const float* dd = sD[px];
        const float v = (sW[px][0] * dd[bi]      + sW[px][1] * dd[bi + 1] +
                         sW[px][2] * dd[bi + 10] + sW[px][3] * dd[bi + 11]) * 0.0625f;
        const int hwp = ((tr4 + (px >> 3)) << 6) + tc8 + (px & 7);
        out[((size_t)b * 324 + lvl * KK + k) * HWP + hwp] = v;
    }
}

// ---------- fallback (Round-2 verified, original layouts) ----------
__global__ __launch_bounds__(128) void corr_level_kernel(
    const float* __restrict__ f1, const float* __restrict__ f2,
    const float* __restrict__ coords, float* __restrict__ out,
    int H2, int W2, float scale, int lvl)
{
    __shared__ float sf1[256];
    __shared__ float sDl[100];
    const int pix = blockIdx.x;
    const int b   = pix >> 12;
    const int hw  = pix & 4095;
    const int t   = threadIdx.x;
    for (int c = t; c < 256; c += 128)
        sf1[c] = f1[((size_t)b * 256 + c) * 4096 + hw];
    __syncthreads();
    const float xs = coords[((size_t)b * 2 + 0) * 4096 + hw] * scale;
    const float ys = coords[((size_t)b * 2 + 1) * 4096 + hw] * scale;
    const float x0f = floorf(xs), y0f = floorf(ys);
    const float fx = xs - x0f, fy = ys - y0f;
    const int ix0 = (int)x0f, iy0 = (int)y0f;
    if (t < 100) {
        const int p = t / 10, q = t - p * 10;
        const int row = iy0 - 4 + p, col = ix0 - 4 + q;
        float acc = 0.0f;
        if (row >= 0 && row < H2 && col >= 0 && col < W2) {
            const size_t step = (size_t)H2 * W2;
            const size_t base = (size_t)b * 256 * step + (size_t)row * W2 + col;
            #pragma unroll 4
            for (int c = 0; c < 256; ++c)
                acc += f2[base + (size_t)c * step] * sf1[c];
        }
        sDl[t] = acc;
    }
    __syncthreads();
    if (t < 81) {
        const int p = t / 9, q = t - p * 9;
        const float d00 = sDl[p * 10 + q];
        const float d01 = sDl[p * 10 + q + 1];
        const float d10 = sDl[p * 10 + q + 10];
        const float d11 = sDl[p * 10 + q + 11];
        const float v = (1.0f - fy) * ((1.0f - fx) * d00 + fx * d01)
                      + fy * ((1.0f - fx) * d10 + fx * d11);
        out[((size_t)b * 324 + (size_t)lvl * 81 + t) * 4096 + hw] = v * 0.0625f;
    }
}

extern "C" void kernel_launch(void* const* d_in, const int* in_sizes, int n_in,
                              void* d_out, int out_size, void* d_ws, size_t ws_size,
                              hipStream_t stream) {
    (void)out_size;
    const float* f1     = (const float*)d_in[0];
    const float* f2l[4] = {(const float*)d_in[1], (const float*)d_in[2],
                           (const float*)d_in[3], (const float*)d_in[4]};
    const float* coords = (const float*)d_in[5];

    // Size-based identification (input order proved unreliable in R1).
    {
        int nbig = 0;
        for (int i = 0; i < n_in; ++i) {
            const int sz = in_sizes[i];
            if (sz == 2097152) {
                if (nbig == 0) f1 = (const float*)d_in[i];
                else           f2l[0] = (const float*)d_in[i];
                ++nbig;
            }
            else if (sz == 524288) f2l[1] = (const float*)d_in[i];
            else if (sz == 131072) f2l[2] = (const float*)d_in[i];
            else if (sz ==  32768) f2l[3] = (const float*)d_in[i];
            else if (sz ==  16384) coords = (const float*)d_in[i];
        }
    }
    float* out = (float*)d_out;
    char*  wsB = (char*)d_ws;

    if (ws_size >= (size_t)OFF_END) {
        stage_kernel<<<dim3(298, 8, 2), dim3(32, 8, 1), 0, stream>>>(
            f1, f2l[0], f2l[1], f2l[2], f2l[3], wsB);
        corr_mfma_kernel<<<dim3(256, 4, 1), 256, 0, stream>>>(wsB, coords, out);
    } else {
        for (int lvl = 0; lvl < 4; ++lvl) {
            const int W2 = 64 >> lvl;
            const float scale = 1.0f / (float)(1 << lvl);
            corr_level_kernel<<<8192, 128, 0, stream>>>(
                f1, f2l[lvl], coords, out, W2, W2, scale, lvl);
        }
    }
}

// Round 12
// 43.993 us; speedup vs baseline: 1.0680x; 1.0368x over previous
//
#include <hip/hip_runtime.h>

#define RADIUS 4
#define KK 81
#define HWP 4096

typedef _Float16 f16x8 __attribute__((ext_vector_type(8)));
typedef float    f32x4 __attribute__((ext_vector_type(4)));

// ws byte-offset layout (f16 channel-last staging)
#define OFF_F1T  0u
#define OFF_L0   4194304u
#define OFF_L1   8388608u
#define OFF_L2   9437184u
#define OFF_L3   9699328u
#define OFF_ZPAD 9764864u        // 512 B of zeros (filled by stage_kernel block 0)
#define OFF_END  9765376u

// ---------- fused staging: all 5 transposes (f32 [B,256,S] -> f16 [B,S,256]) ----------
// Scalar variant: measured better than the vectorized version (R9 +0.8us).
__global__ __launch_bounds__(256) void stage_kernel(
    const float* __restrict__ f1, const float* __restrict__ l0,
    const float* __restrict__ l1, const float* __restrict__ l2,
    const float* __restrict__ l3, char* __restrict__ wsB)
{
    __shared__ float tile[32][33];
    const int bx = blockIdx.x;    // 0..297
    const int b  = blockIdx.z;
    const int r0 = blockIdx.y * 32;
    const int tx = threadIdx.x, ty = threadIdx.y;   // 32 x 8
    if (bx == 0 && blockIdx.y == 0 && b == 0) {
        const int tt = ty * 32 + tx;
        if (tt < 128) ((float*)(wsB + OFF_ZPAD))[tt] = 0.0f;   // zero pad record
    }
    const float* src; _Float16* dst; int S, s0i;
    if (bx < 128)      { src = f1; dst = (_Float16*)(wsB + OFF_F1T); S = 4096; s0i = bx; }
    else if (bx < 256) { src = l0; dst = (_Float16*)(wsB + OFF_L0);  S = 4096; s0i = bx - 128; }
    else if (bx < 288) { src = l1; dst = (_Float16*)(wsB + OFF_L1);  S = 1024; s0i = bx - 256; }
    else if (bx < 296) { src = l2; dst = (_Float16*)(wsB + OFF_L2);  S = 256;  s0i = bx - 288; }
    else               { src = l3; dst = (_Float16*)(wsB + OFF_L3);  S = 64;   s0i = bx - 296; }
    const int s0 = s0i * 32;
    src += (size_t)b * 256 * S;
    dst += (size_t)b * S * 256;
    #pragma unroll
    for (int i = 0; i < 32; i += 8)
        tile[ty + i][tx] = src[(size_t)(r0 + ty + i) * S + s0 + tx];
    __syncthreads();
    #pragma unroll
    for (int i = 0; i < 32; i += 8)
        dst[(size_t)(s0 + ty + i) * 256 + r0 + tx] = (_Float16)tile[tx][ty + i];
}

// ---------- main: 8x4-pixel tiles (32 px), paired-unit LDS pipeline ----------
// CHAMPION (R8, measured 43.96us): R2 skeleton + sD stride 106 (scatter groups
// land 2 lanes/bank = free; fixes the 1.1-2.4M SQ_LDS_BANK_CONFLICT measured in
// R0/R6) + s_setprio(1) around the MFMA cluster (T5; phases have wave role split).
// 12-round ledger: all macro-mechanisms (lockstep vs barrier-free, counted-vmcnt,
// XCD mapping, bytes/2, coalescing) tested and neutral-to-worse; only these
// micro-fixes reproduced. This configuration is the empirical floor found.
__global__ __launch_bounds__(256, 3) void corr_mfma_kernel(
    const char* __restrict__ wsB,
    const float* __restrict__ coords,
    float* __restrict__ out)           // [B,324,4096]
{
    __shared__ f32x4 sB[2][1024];      // 2 x 16KB (two 8-KB unit-halves each)
    __shared__ float sD[32][106];      // per-px 10x10 window dots (padded stride)
    __shared__ int   sIx[32], sIy[32];
    __shared__ float sW[32][4];
    __shared__ int   sBox[5];          // rlo, cfi, ntw, ntot, inv

    char* sBb = (char*)sB;

    const int bx   = blockIdx.x;                  // 0..255
    const int lvl  = blockIdx.y;                  // 0..3
    const int tile = ((bx & 7) << 5) | (bx >> 3); // XCD swizzle (bijective on 256)
    const int b    = tile >> 7;
    const int t7   = tile & 127;                  // 128 tiles per batch: 16 rows x 8 cols
    const int tr4  = (t7 >> 3) << 2;              // tile pixel-row base (4 tall)
    const int tc8  = (t7 & 7) << 3;               // tile pixel-col base (8 wide)
    const int t    = threadIdx.x;                 // 0..255
    const int l    = t & 63;
    const int wid  = t >> 6;                      // wave 0..3
    const int aset = wid & 1;                     // which 16-px A tile
    const int half = wid >> 1;                    // which unit of the pair

    const int sh = 6 - lvl;
    const int W2 = 1 << sh;

    for (int i = t; i < 32 * 106; i += 256)
        ((float*)sD)[i] = 0.0f;

    if (t < 32) {
        const int hwc = ((tr4 + (t >> 3)) << 6) + tc8 + (t & 7);
        const float sc = 1.0f / (float)(1 << lvl);
        const float xs = coords[((size_t)b * 2 + 0) * HWP + hwc] * sc;
        const float ys = coords[((size_t)b * 2 + 1) * HWP + hwc] * sc;
        const float x0f = floorf(xs), y0f = floorf(ys);
        sIx[t] = (int)x0f; sIy[t] = (int)y0f;
        const float fx = xs - x0f, fy = ys - y0f;
        sW[t][0] = (1.f - fx) * (1.f - fy);
        sW[t][1] = fx * (1.f - fy);
        sW[t][2] = (1.f - fx) * fy;
        sW[t][3] = fx * fy;
    }
    __syncthreads();
    if (t == 0) {
        int rlo = 1 << 20, rhi = -(1 << 20), clo = 1 << 20, chi = -(1 << 20);
        for (int px = 0; px < 32; ++px) {
            rlo = min(rlo, sIy[px]); rhi = max(rhi, sIy[px]);
            clo = min(clo, sIx[px]); chi = max(chi, sIx[px]);
        }
        const int rl = max(rlo - RADIUS, 0);
        const int rh = min(rhi + RADIUS + 1, W2 - 1);
        const int cf = max(clo - RADIUS, 0);
        const int ce = min(chi + RADIUS + 1, W2 - 1);
        const int nr = rh - rl + 1;
        const int nt = (ce >= cf) ? ((ce - cf + 16) >> 4) : 0;
        sBox[0] = rl;
        sBox[1] = cf;
        sBox[2] = nt;
        sBox[3] = (nr > 0) ? nr * nt : 0;
        sBox[4] = 65535 / max(nt, 1) + 1;     // exact u/nt = (u*inv)>>16 for u<512,nt<=8
    }

    // A fragments (verified R9 mapping): lane l = local px (l&15) in A-set, k-chunk (l>>4)
    const int pxl = (aset << 4) + (l & 15);
    const int hwA = ((tr4 + (pxl >> 3)) << 6) + tc8 + (pxl & 7);
    const char* ap = wsB + OFF_F1T + ((size_t)(b * HWP + hwA)) * 512 + ((l >> 4) << 4);
    const f16x8 a0 = __builtin_bit_cast(f16x8, *(const f32x4*)(ap));
    const f16x8 a1 = __builtin_bit_cast(f16x8, *(const f32x4*)(ap + 64));
    const f16x8 a2 = __builtin_bit_cast(f16x8, *(const f32x4*)(ap + 128));
    const f16x8 a3 = __builtin_bit_cast(f16x8, *(const f32x4*)(ap + 192));
    const f16x8 a4 = __builtin_bit_cast(f16x8, *(const f32x4*)(ap + 256));
    const f16x8 a5 = __builtin_bit_cast(f16x8, *(const f32x4*)(ap + 320));
    const f16x8 a6 = __builtin_bit_cast(f16x8, *(const f32x4*)(ap + 384));
    const f16x8 a7 = __builtin_bit_cast(f16x8, *(const f32x4*)(ap + 448));
    __syncthreads();                      // publish sBox

    const int rlo = sBox[0], cfi = sBox[1], ntw = sBox[2];
    const int ntot = sBox[3], inv = sBox[4];
    const int NP = (ntot + 1) >> 1;       // phases (2 units each)
    const unsigned lvbase = ((lvl == 0) ? OFF_L0 : (lvl == 1) ? OFF_L1
                           : (lvl == 2) ? OFF_L2 : OFF_L3)
                          + (((unsigned)b << (2 * sh)) << 9);
    const int coff = l & 15;

    const int pxg  = (aset << 4) + ((l >> 4) << 2);  // this lane's 4 scatter pixels
    const int iy0r = sIy[pxg + 0], ix0r = sIx[pxg + 0];
    const int iy1r = sIy[pxg + 1], ix1r = sIx[pxg + 1];
    const int iy2r = sIy[pxg + 2], ix2r = sIx[pxg + 2];
    const int iy3r = sIy[pxg + 3], ix3r = sIx[pxg + 3];

// stage loads for phase P: thread t serves unit u=2P+(t>>7), px (t&15), 64B at chunk-group (t>>4)&7
#define LOADP(P_, R0_, R1_, R2_, R3_) { \
        const int u_ = ((P_) << 1) + (t >> 7); \
        const unsigned q_ = ((unsigned)(u_ * inv)) >> 16; \
        const int j_ = u_ - (int)q_ * ntw; \
        const int col_ = cfi + (j_ << 4) + (t & 15); \
        const bool ok_ = (u_ < ntot) && ((unsigned)col_ < (unsigned)W2); \
        const int row_ = rlo + (int)q_; \
        const char* gp_ = wsB + (ok_ ? (lvbase + ((unsigned)((row_ << sh) + col_) << 9)) \
                                     : OFF_ZPAD) + ((unsigned)((t >> 4) & 7) << 6); \
        R0_ = *(const f32x4*)(gp_); \
        R1_ = *(const f32x4*)(gp_ + 16); \
        R2_ = *(const f32x4*)(gp_ + 32); \
        R3_ = *(const f32x4*)(gp_ + 48); \
        __builtin_amdgcn_sched_barrier(0); }

// LDS layout per 8-KB half: byte = g*256 + px*16 (granule g = 16B of channels), proven R1 map
#define WRITEP(BUF_, R0_, R1_, R2_, R3_) { \
        char* wp_ = sBb + ((BUF_) << 14) + ((t >> 7) << 13) + (((t >> 4) & 7) << 10) \
                  + ((t & 15) << 4); \
        *(f32x4*)(wp_)       = R0_; \
        *(f32x4*)(wp_ + 256) = R1_; \
        *(f32x4*)(wp_ + 512) = R2_; \
        *(f32x4*)(wp_ + 768) = R3_; }

// consume this wave's unit of phase P: 8 ds_read_b128 + 8 MFMA (setprio-wrapped) + scatter
#define CONSUMEP(BUF_, P_) { \
        const int u_ = ((P_) << 1) + half; \
        if (u_ < ntot) { \
            const unsigned q_ = ((unsigned)(u_ * inv)) >> 16; \
            const int j_ = u_ - (int)q_ * ntw; \
            const int row_ = rlo + (int)q_; \
            const char* lb_ = sBb + ((BUF_) << 14) + (half << 13) + ((l >> 4) << 8) \
                            + ((l & 15) << 4); \
            const f16x8 b0_ = __builtin_bit_cast(f16x8, *(const f32x4*)(lb_)); \
            const f16x8 b1_ = __builtin_bit_cast(f16x8, *(const f32x4*)(lb_ + 1024)); \
            const f16x8 b2_ = __builtin_bit_cast(f16x8, *(const f32x4*)(lb_ + 2048)); \
            const f16x8 b3_ = __builtin_bit_cast(f16x8, *(const f32x4*)(lb_ + 3072)); \
            const f16x8 b4_ = __builtin_bit_cast(f16x8, *(const f32x4*)(lb_ + 4096)); \
            const f16x8 b5_ = __builtin_bit_cast(f16x8, *(const f32x4*)(lb_ + 5120)); \
            const f16x8 b6_ = __builtin_bit_cast(f16x8, *(const f32x4*)(lb_ + 6144)); \
            const f16x8 b7_ = __builtin_bit_cast(f16x8, *(const f32x4*)(lb_ + 7168)); \
            f32x4 ac0 = {0.f, 0.f, 0.f, 0.f}; \
            f32x4 ac1 = {0.f, 0.f, 0.f, 0.f}; \
            __builtin_amdgcn_s_setprio(1); \
            ac0 = __builtin_amdgcn_mfma_f32_16x16x32_f16(a0, b0_, ac0, 0, 0, 0); \
            ac1 = __builtin_amdgcn_mfma_f32_16x16x32_f16(a1, b1_, ac1, 0, 0, 0); \
            ac0 = __builtin_amdgcn_mfma_f32_16x16x32_f16(a2, b2_, ac0, 0, 0, 0); \
            ac1 = __builtin_amdgcn_mfma_f32_16x16x32_f16(a3, b3_, ac1, 0, 0, 0); \
            ac0 = __builtin_amdgcn_mfma_f32_16x16x32_f16(a4, b4_, ac0, 0, 0, 0); \
            ac1 = __builtin_amdgcn_mfma_f32_16x16x32_f16(a5, b5_, ac1, 0, 0, 0); \
            ac0 = __builtin_amdgcn_mfma_f32_16x16x32_f16(a6, b6_, ac0, 0, 0, 0); \
            ac1 = __builtin_amdgcn_mfma_f32_16x16x32_f16(a7, b7_, ac1, 0, 0, 0); \
            __builtin_amdgcn_s_setprio(0); \
            const f32x4 accs = ac0 + ac1; \
            const int col_ = cfi + (j_ << 4) + coff; \
            const int p0 = row_ - iy0r + RADIUS, q0 = col_ - ix0r + RADIUS; \
            if ((unsigned)p0 < 10u && (unsigned)q0 < 10u) sD[pxg + 0][p0 * 10 + q0] = accs[0]; \
            const int p1 = row_ - iy1r + RADIUS, q1 = col_ - ix1r + RADIUS; \
            if ((unsigned)p1 < 10u && (unsigned)q1 < 10u) sD[pxg + 1][p1 * 10 + q1] = accs[1]; \
            const int p2 = row_ - iy2r + RADIUS, q2 = col_ - ix2r + RADIUS; \
            if ((unsigned)p2 < 10u && (unsigned)q2 < 10u) sD[pxg + 2][p2 * 10 + q2] = accs[2]; \
            const int p3 = row_ - iy3r + RADIUS, q3 = col_ - ix3r + RADIUS; \
            if ((unsigned)p3 < 10u && (unsigned)q3 < 10u) sD[pxg + 3][p3 * 10 + q3] = accs[3]; \
        } }

    {
        f32x4 XA, XB, XC, XD, YA, YB, YC, YD;
        if (ntot > 0) {
            LOADP(0, XA, XB, XC, XD);
            if (NP > 1) LOADP(1, YA, YB, YC, YD);
            WRITEP(0, XA, XB, XC, XD);
        }
        __syncthreads();                         // buf0 ready
        if (ntot > 0) {
            int p = 0;
            for (;;) {
                // body A: X free -> prefetch p+2; consume p; publish p+1 (Y)
                if (p + 2 < NP) LOADP(p + 2, XA, XB, XC, XD);
                CONSUMEP(p & 1, p);
                if (p + 1 < NP) WRITEP((p + 1) & 1, YA, YB, YC, YD);
                __syncthreads();
                if (++p >= NP) break;
                // body B: roles swapped (static reg names, rule #20)
                if (p + 2 < NP) LOADP(p + 2, YA, YB, YC, YD);
                CONSUMEP(p & 1, p);
                if (p + 1 < NP) WRITEP((p + 1) & 1, XA, XB, XC, XD);
                __syncthreads();
                if (++p >= NP) break;
            }
        }
    }
#undef LOADP
#undef WRITEP
#undef CONSUMEP
    __syncthreads();

    // bilinear combine + store (this level's 81 channels, 32 pixels)
    for (int j = t; j < 32 * KK; j += 256) {
        const int px = j & 31;
        const int k  = j >> 5;           // 0..80
        const int p  = (k * 57) >> 9;    // k/9
        const int q  = k - p * 9;
        const int bi = p * 10 + q;
        const float* dd = sD[px];
        const float v = (sW[px][0] * dd[bi]      + sW[px][1] * dd[bi + 1] +
                         sW[px][2] * dd[bi + 10] + sW[px][3] * dd[bi + 11]) * 0.0625f;
        const int hwp = ((tr4 + (px >> 3)) << 6) + tc8 + (px & 7);
        out[((size_t)b * 324 + lvl * KK + k) * HWP + hwp] = v;
    }
}

// ---------- fallback (Round-2 verified, original layouts) ----------
__global__ __launch_bounds__(128) void corr_level_kernel(
    const float* __restrict__ f1, const float* __restrict__ f2,
    const float* __restrict__ coords, float* __restrict__ out,
    int H2, int W2, float scale, int lvl)
{
    __shared__ float sf1[256];
    __shared__ float sDl[100];
    const int pix = blockIdx.x;
    const int b   = pix >> 12;
    const int hw  = pix & 4095;
    const int t   = threadIdx.x;
    for (int c = t; c < 256; c += 128)
        sf1[c] = f1[((size_t)b * 256 + c) * 4096 + hw];
    __syncthreads();
    const float xs = coords[((size_t)b * 2 + 0) * 4096 + hw] * scale;
    const float ys = coords[((size_t)b * 2 + 1) * 4096 + hw] * scale;
    const float x0f = floorf(xs), y0f = floorf(ys);
    const float fx = xs - x0f, fy = ys - y0f;
    const int ix0 = (int)x0f, iy0 = (int)y0f;
    if (t < 100) {
        const int p = t / 10, q = t - p * 10;
        const int row = iy0 - 4 + p, col = ix0 - 4 + q;
        float acc = 0.0f;
        if (row >= 0 && row < H2 && col >= 0 && col < W2) {
            const size_t step = (size_t)H2 * W2;
            const size_t base = (size_t)b * 256 * step + (size_t)row * W2 + col;
            #pragma unroll 4
            for (int c = 0; c < 256; ++c)
                acc += f2[base + (size_t)c * step] * sf1[c];
        }
        sDl[t] = acc;
    }
    __syncthreads();
    if (t < 81) {
        const int p = t / 9, q = t - p * 9;
        const float d00 = sDl[p * 10 + q];
        const float d01 = sDl[p * 10 + q + 1];
        const float d10 = sDl[p * 10 + q + 10];
        const float d11 = sDl[p * 10 + q + 11];
        const float v = (1.0f - fy) * ((1.0f - fx) * d00 + fx * d01)
                      + fy * ((1.0f - fx) * d10 + fx * d11);
        out[((size_t)b * 324 + (size_t)lvl * 81 + t) * 4096 + hw] = v * 0.0625f;
    }
}

extern "C" void kernel_launch(void* const* d_in, const int* in_sizes, int n_in,
                              void* d_out, int out_size, void* d_ws, size_t ws_size,
                              hipStream_t stream) {
    (void)out_size;
    const float* f1     = (const float*)d_in[0];
    const float* f2l[4] = {(const float*)d_in[1], (const float*)d_in[2],
                           (const float*)d_in[3], (const float*)d_in[4]};
    const float* coords = (const float*)d_in[5];

    // Size-based identification (input order proved unreliable in R1).
    {
        int nbig = 0;
        for (int i = 0; i < n_in; ++i) {
            const int sz = in_sizes[i];
            if (sz == 2097152) {
                if (nbig == 0) f1 = (const float*)d_in[i];
                else           f2l[0] = (const float*)d_in[i];
                ++nbig;
            }
            else if (sz == 524288) f2l[1] = (const float*)d_in[i];
            else if (sz == 131072) f2l[2] = (const float*)d_in[i];
            else if (sz ==  32768) f2l[3] = (const float*)d_in[i];
            else if (sz ==  16384) coords = (const float*)d_in[i];
        }
    }
    float* out = (float*)d_out;
    char*  wsB = (char*)d_ws;

    if (ws_size >= (size_t)OFF_END) {
        stage_kernel<<<dim3(298, 8, 2), dim3(32, 8, 1), 0, stream>>>(
            f1, f2l[0], f2l[1], f2l[2], f2l[3], wsB);
        corr_mfma_kernel<<<dim3(256, 4, 1), 256, 0, stream>>>(wsB, coords, out);
    } else {
        for (int lvl = 0; lvl < 4; ++lvl) {
            const int W2 = 64 >> lvl;
            const float scale = 1.0f / (float)(1 << lvl);
            corr_level_kernel<<<8192, 128, 0, stream>>>(
                f1, f2l[lvl], coords, out, W2, W2, scale, lvl);
        }
    }
}